// Round 8
// baseline (423.090 us; speedup 1.0000x reference)
//
#include <hip/hip_runtime.h>
#include <math.h>

// ---------------------------------------------------------------------------
// PPFNet pipeline on MI355X. B=16 clouds x 2048 pts, K=16 knn, all f32.
// 2 launches.
// Codegen lessons (r6/r7): (1) __launch_bounds__ 2nd arg > 4 => allocator
// targets ~32 VGPR and spills h1[32] to scratch (VALUBusy 2%). (2) Writing
// per-chunk results straight to LDS (dropping the h2r[32] array) lets the
// allocator squeeze to 28 VGPR and churn AGPR moves (~10x VALU issue,
// 113us). Keep the register working set EXPLICIT (h2r[32]) and bounds <= 4.
//  K1 knn_conv1 : block = 256 = 16 points x 16 slices; whole cloud in LDS.
//     A: med3 top-4/slice of s=|c|^2-2p.c; B: shuffle bitonic -> tau;
//     C: rescan collect; D: exact-d2 fixup; E: nbr+ppf (poly atan2);
//     fused conv1 (edge-local) + gfromh (node-local) -> nbr, ppf, G.
//     Also zeroes the per-cloud fc counters for K2.
//  K2 conv2_pool: 1 edge/thread: relu(G[j] + ppf@W2a[32:36]) -> 32x32 ->
//     16-lane shfl max -> block reduce -> int atomicMax per cloud
//     (h2>=0: int-compare order-preserving; 0xAA poison negative=identity).
//     Last block per cloud (threadfence + atomic counter) computes the
//     Linear(32,40) classifier for that cloud -> no separate fc launch.
// ---------------------------------------------------------------------------

#define NPER 2048
#define NCLOUD 16

// ws layout (bytes)
#define OFF_NBR  (size_t)(0u)          // int   [N][16]    (2 MB)
#define OFF_PPF  (size_t)(2u << 20)    // float [N][16][4] (8 MB)
#define OFF_G    (size_t)(10u << 20)   // float [N][32]    (4 MB)
#define OFF_POOL (size_t)(14u << 20)   // int   [16][32]   (2 KB)
#define OFF_CNT  ((size_t)(14u << 20) + 4096u)  // int [16]

__device__ __forceinline__ float med3(float a, float b, float c) {
    return __builtin_amdgcn_fmed3f(a, b, c);
}
__device__ __forceinline__ void cex(float& a, float& b) {
    const float lo = fminf(a, b), hi = fmaxf(a, b); a = lo; b = hi;
}
__device__ __forceinline__ void bmerge8(float (&v)[8]) {
#pragma unroll
    for (int i = 0; i < 4; ++i) cex(v[i], v[i + 4]);
#pragma unroll
    for (int b = 0; b < 8; b += 4)
#pragma unroll
        for (int i = 0; i < 2; ++i) cex(v[b + i], v[b + i + 2]);
#pragma unroll
    for (int b = 0; b < 8; b += 2) cex(v[b], v[b + 1]);
}
__device__ __forceinline__ void bmerge16(float (&v)[16]) {
#pragma unroll
    for (int i = 0; i < 8; ++i) cex(v[i], v[i + 8]);
#pragma unroll
    for (int b = 0; b < 16; b += 8)
#pragma unroll
        for (int i = 0; i < 4; ++i) cex(v[b + i], v[b + i + 4]);
#pragma unroll
    for (int b = 0; b < 16; b += 4)
#pragma unroll
        for (int i = 0; i < 2; ++i) cex(v[b + i], v[b + i + 2]);
#pragma unroll
    for (int b = 0; b < 16; b += 2) cex(v[b], v[b + 1]);
}

// atan2(y,x) with y >= 0, range [0,pi]. A&S 4.4.49 poly, err ~1e-6 rad.
__device__ __forceinline__ float fast_atan2p(float y, float x) {
    const float ax = fabsf(x);
    const float mn = fminf(ax, y), mx = fmaxf(ax, y);
    float a = mn * __builtin_amdgcn_rcpf(mx);
    a = (mx == 0.f) ? 0.f : a;
    const float t = a * a;
    float p = fmaf(t, 0.0028662257f, -0.0161657367f);
    p = fmaf(t, p, 0.0429096138f);
    p = fmaf(t, p, -0.0752896400f);
    p = fmaf(t, p, 0.1065626393f);
    p = fmaf(t, p, -0.1420889944f);
    p = fmaf(t, p, 0.1999355085f);
    p = fmaf(t, p, -0.3333314528f);
    float r = fmaf(a * t, p, a);                 // atan(a), a in [0,1]
    r = (y > ax) ? (1.5707963268f - r) : r;
    r = (x < 0.f) ? (3.1415926536f - r) : r;
    return r;
}

__device__ __forceinline__ float angf(float ax, float ay, float az,
                                      float bx, float by, float bz) {
    const float cx = ay * bz - az * by;
    const float cy = az * bx - ax * bz;
    const float cz = ax * by - ay * bx;
    const float cn = sqrtf(cx * cx + cy * cy + cz * cz);
    const float dt = ax * bx + ay * by + az * bz;
    return fast_atan2p(cn, dt);
}

// ---------------------------------------------------------------------------
// K1: knn + ppf + conv1 + gfromh. Block = 256 = 16 points x 16 slices.
// Grid = 2048. LDS ~33.5 KB -> 4 blocks/CU.
// ---------------------------------------------------------------------------
__global__ __launch_bounds__(256) void knn_conv1(const float* __restrict__ pos,
                                                 const float* __restrict__ nrm,
                                                 const float* __restrict__ W1a,
                                                 const float* __restrict__ b1a,
                                                 const float* __restrict__ W1b,
                                                 const float* __restrict__ b1b,
                                                 const float* __restrict__ W2a,
                                                 const float* __restrict__ b2a,
                                                 int* __restrict__ nbr,
                                                 float* __restrict__ ppf,
                                                 float* __restrict__ G,
                                                 int* __restrict__ ccnt) {
    const int tid = threadIdx.x;
    const int pl  = tid >> 4;               // point within block (0..15)
    const int sl  = tid & 15;               // slice / lane-in-node (0..15)
    const int gp  = blockIdx.x * 16 + pl;   // global point
    const int cloud = gp >> 11;
    const int lp  = gp & 2047;              // local point idx in cloud
    const int cbase = cloud * NPER;

    // zero the fc last-block counters for K2 (kernel boundary = fence)
    if (blockIdx.x == 0 && tid < NCLOUD) ccnt[tid] = 0;

    __shared__ float4 tile[2048];           // x,y,z,|c|^2  (32 KB)
    __shared__ unsigned short hiL[16][40];  // hit local indices (1.25 KB)
    __shared__ int cnt[16];

    if (tid < 16) cnt[tid] = 0;

#pragma unroll
    for (int c = 0; c < 8; ++c) {
        const int idx = c * 256 + tid;
        const float x = pos[(cbase + idx) * 3 + 0];
        const float y = pos[(cbase + idx) * 3 + 1];
        const float z = pos[(cbase + idx) * 3 + 2];
        tile[idx] = make_float4(x, y, z, x * x + y * y + z * z);
    }
    __syncthreads();

    const float4 P  = tile[lp];
    const float pn2 = P.w;
    const float m2x = -2.f * P.x, m2y = -2.f * P.y, m2z = -2.f * P.z;

    // ---- Phase A: top-4 of s per slice (128 candidates), branchless ----
    float dl[4];
#pragma unroll
    for (int m = 0; m < 4; ++m) dl[m] = INFINITY;

#pragma unroll 4
    for (int jj = 0; jj < 128; ++jj) {
        const int cand = jj * 16 + sl;
        const float4 C = tile[cand];
        float s = fmaf(m2x, C.x, fmaf(m2y, C.y, fmaf(m2z, C.z, C.w)));
        s = (cand == lp) ? INFINITY : s;
        dl[3] = med3(dl[2], dl[3], s);
        dl[2] = med3(dl[1], dl[2], s);
        dl[1] = med3(dl[0], dl[1], s);
        dl[0] = fminf(dl[0], s);
    }

    // ---- Phase B: shuffle bitonic merge of 16 sorted-4 lists -> tau ----
    float tau_s;
    {
        float v8[8];
#pragma unroll
        for (int i = 0; i < 4; ++i) v8[i] = dl[i];
#pragma unroll
        for (int i = 0; i < 4; ++i) v8[7 - i] = __shfl_xor(dl[i], 1);
        bmerge8(v8);
        float v[16];
#pragma unroll
        for (int i = 0; i < 8; ++i) v[i] = v8[i];
#pragma unroll
        for (int i = 0; i < 8; ++i) v[15 - i] = __shfl_xor(v8[i], 2);
        bmerge16(v);
        {
            float p[16];
#pragma unroll
            for (int i = 0; i < 16; ++i) p[i] = __shfl_xor(v[i], 4);
            float w[16];
#pragma unroll
            for (int i = 0; i < 16; ++i) w[i] = fminf(v[i], p[15 - i]);
            bmerge16(w);
#pragma unroll
            for (int i = 0; i < 16; ++i) v[i] = w[i];
        }
        {
            float p[16];
#pragma unroll
            for (int i = 0; i < 16; ++i) p[i] = __shfl_xor(v[i], 8);
            float t = -INFINITY;
#pragma unroll
            for (int i = 0; i < 16; ++i) t = fmaxf(t, fminf(v[i], p[15 - i]));
            tau_s = t;
        }
    }
    const float tsw = tau_s + 6e-5f * (1.f + pn2 + fabsf(tau_s + pn2));

    // ---- Phase C: rescan on s, collect hit indices ----
#pragma unroll 4
    for (int jj = 0; jj < 128; ++jj) {
        const int cand = jj * 16 + sl;
        const float4 C = tile[cand];
        const float s = fmaf(m2x, C.x, fmaf(m2y, C.y, fmaf(m2z, C.z, C.w)));
        if (s <= tsw && cand != lp) {
            const int k = atomicAdd(&cnt[pl], 1);
            if (k < 40) hiL[pl][k] = (unsigned short)cand;
        }
    }
    __syncthreads();

    // ---- Phase D: exact top-16 (bit-identical d2, index tiebreak) ----
    if (tid < 16) {
        int n = cnt[tid];
        n = n > 40 ? 40 : n;
        if (n != 16) {
            const int myl = (blockIdx.x * 16 + tid) & 2047;
            const float4 Q = tile[myl];
            unsigned long long keys[16];
#pragma unroll
            for (int m = 0; m < 16; ++m) keys[m] = ~0ULL;
            for (int i = 0; i < n; ++i) {
                const int cand = hiL[tid][i];
                const float4 C = tile[cand];
                const float dx = __fsub_rn(Q.x, C.x);
                const float dy = __fsub_rn(Q.y, C.y);
                const float dz = __fsub_rn(Q.z, C.z);
                const float d2 = __fadd_rn(__fadd_rn(__fmul_rn(dx, dx),
                                                     __fmul_rn(dy, dy)),
                                           __fmul_rn(dz, dz));
                const unsigned long long key =
                    ((unsigned long long)__float_as_uint(d2) << 32) |
                    (unsigned int)cand;
                if (key < keys[15]) {
#pragma unroll
                    for (int m = 15; m >= 1; --m) {
                        const bool up   = key < keys[m - 1];
                        const bool here = key < keys[m];
                        keys[m] = up ? keys[m - 1] : (here ? key : keys[m]);
                    }
                    if (key < keys[0]) keys[0] = key;
                }
            }
#pragma unroll
            for (int m = 0; m < 16; ++m)
                hiL[tid][m] = (unsigned short)(keys[m] & 0xFFFFu);
        }
    }
    __syncthreads();

    // ---- Phase E: nbr + ppf (1 edge per thread, ppf kept in regs) ----
    const float nix = nrm[gp * 3 + 0], niy = nrm[gp * 3 + 1], niz = nrm[gp * 3 + 2];
    float4 x;
    {
        const int jl = hiL[pl][sl];
        const int j  = cbase + jl;
        nbr[gp * 16 + sl] = j;
        const float4 C = tile[jl];
        const float njx = nrm[j * 3 + 0], njy = nrm[j * 3 + 1], njz = nrm[j * 3 + 2];
        const float dx = C.x - P.x, dy = C.y - P.y, dz = C.z - P.z;
        x.x = sqrtf(dx * dx + dy * dy + dz * dz);
        x.y = angf(nix, niy, niz, dx, dy, dz);
        x.z = angf(njx, njy, njz, dx, dy, dz);
        x.w = angf(nix, niy, niz, njx, njy, njz);
        ((float4*)ppf)[(size_t)gp * 16 + sl] = x;
    }

    // ---- FUSED conv1: layer1 (4->32) on this edge ----
    float h1[32];
#pragma unroll
    for (int o = 0; o < 32; ++o) {
        h1[o] = fmaxf(fmaf(x.x, W1a[o],
                     fmaf(x.y, W1a[32 + o],
                     fmaf(x.z, W1a[64 + o],
                     fmaf(x.w, W1a[96 + o], b1a[o])))), 0.f);
    }

    // ---- layer2 (32->32) in 4x8 chunks + 16-lane max; all lanes keep h ----
    float hr[32];
#pragma unroll 1
    for (int ob = 0; ob < 4; ++ob) {
        float acc[8];
#pragma unroll
        for (int u = 0; u < 8; ++u) acc[u] = b1b[ob * 8 + u];
#pragma unroll
        for (int hh = 0; hh < 32; ++hh) {
            const float hv = h1[hh];
#pragma unroll
            for (int u = 0; u < 8; ++u)
                acc[u] = fmaf(hv, W1b[hh * 32 + ob * 8 + u], acc[u]);
        }
#pragma unroll
        for (int u = 0; u < 8; ++u) {
            float v = acc[u];
            v = fmaxf(v, __shfl_xor(v, 1));
            v = fmaxf(v, __shfl_xor(v, 2));
            v = fmaxf(v, __shfl_xor(v, 4));
            v = fmaxf(v, __shfl_xor(v, 8));
            hr[ob * 8 + u] = fmaxf(v, 0.f);
        }
    }

    // ---- FUSED gfromh: G[node] = hr @ W2a[0:32,:] + b2a (2 cols/lane) ----
    {
        const int c0 = sl * 2;
        float g0 = b2a[c0], g1 = b2a[c0 + 1];
#pragma unroll
        for (int k = 0; k < 32; ++k) {
            g0 = fmaf(hr[k], W2a[k * 32 + c0], g0);
            g1 = fmaf(hr[k], W2a[k * 32 + c0 + 1], g1);
        }
        ((float2*)(G + (size_t)gp * 32))[sl] = make_float2(g0, g1);
    }
}

// ---------------------------------------------------------------------------
// K2: conv2 + pool + fc. 1 edge/thread, 16 threads/node, block = 16 nodes.
// Grid 2048 x 256. r5-proven body: h2r[32] explicit, sh written ONCE after
// the chunk loop (keeps the allocator honest). Last block per cloud does fc.
// ---------------------------------------------------------------------------
__global__ __launch_bounds__(256, 4) void conv2_pool(const float* __restrict__ ppf,
                                                     const int* __restrict__ nbr,
                                                     const float* __restrict__ G,
                                                     const float* __restrict__ W2a,
                                                     const float* __restrict__ W2b,
                                                     const float* __restrict__ b2b,
                                                     const float* __restrict__ Wc,
                                                     const float* __restrict__ bc,
                                                     int* __restrict__ pooledi,
                                                     int* __restrict__ ccnt,
                                                     float* __restrict__ out) {
    const int tid    = threadIdx.x;
    const int gid    = blockIdx.x * 256 + tid;    // edge id
    const int node16 = tid >> 4;                  // node within block
    const int cloud  = blockIdx.x >> 7;           // 128 blocks per cloud

    const int j = nbr[gid];

    float h1[32];
    {
        const float4* gr = (const float4*)(G + (size_t)j * 32);
#pragma unroll
        for (int q = 0; q < 8; ++q) {
            const float4 v = gr[q];
            h1[q * 4 + 0] = v.x; h1[q * 4 + 1] = v.y;
            h1[q * 4 + 2] = v.z; h1[q * 4 + 3] = v.w;
        }
    }
    const float4 x = ((const float4*)ppf)[gid];
#pragma unroll
    for (int o = 0; o < 32; ++o) {
        h1[o] = fmaxf(fmaf(x.x, W2a[32 * 32 + o],
                     fmaf(x.y, W2a[33 * 32 + o],
                     fmaf(x.z, W2a[34 * 32 + o],
                     fmaf(x.w, W2a[35 * 32 + o], h1[o])))), 0.f);
    }

    float h2r[32];
#pragma unroll 1
    for (int ob = 0; ob < 4; ++ob) {
        float acc[8];
#pragma unroll
        for (int u = 0; u < 8; ++u) acc[u] = b2b[ob * 8 + u];
#pragma unroll
        for (int hh = 0; hh < 32; ++hh) {
            const float hv = h1[hh];
#pragma unroll
            for (int u = 0; u < 8; ++u)
                acc[u] = fmaf(hv, W2b[hh * 32 + ob * 8 + u], acc[u]);
        }
#pragma unroll
        for (int u = 0; u < 8; ++u) {
            float v = acc[u];
            v = fmaxf(v, __shfl_xor(v, 1));
            v = fmaxf(v, __shfl_xor(v, 2));
            v = fmaxf(v, __shfl_xor(v, 4));
            v = fmaxf(v, __shfl_xor(v, 8));
            h2r[ob * 8 + u] = fmaxf(v, 0.f);
        }
    }

    // ---- block pool: 16 nodes -> 32 channels -> atomicMax per cloud ----
    __shared__ float sh[16][33];
    __shared__ float pv[32];
    __shared__ int lastFlag;
    if ((tid & 15) == 0) {
#pragma unroll
        for (int o = 0; o < 32; ++o) sh[node16][o] = h2r[o];
    }
    __syncthreads();
    if (tid < 32) {
        float m = sh[0][tid];
#pragma unroll
        for (int n = 1; n < 16; ++n) m = fmaxf(m, sh[n][tid]);
        atomicMax(&pooledi[cloud * 32 + tid], __float_as_int(m));
    }

    // ---- fc: last block of this cloud computes the classifier ----
    __threadfence();
    if (tid == 0) lastFlag = (atomicAdd(&ccnt[cloud], 1) == 127);
    __syncthreads();
    if (lastFlag) {
        if (tid < 32) {
            // atomic read (identity max) bypasses stale L1 across XCDs
            const int iv = atomicMax(&pooledi[cloud * 32 + tid],
                                     (int)0x80000000);
            pv[tid] = __int_as_float(iv);
        }
        __syncthreads();
        if (tid < 40) {
            float acc = bc[tid];
#pragma unroll
            for (int o = 0; o < 32; ++o)
                acc = fmaf(pv[o], Wc[o * 40 + tid], acc);
            out[cloud * 40 + tid] = acc;
        }
    }
}

// ---------------------------------------------------------------------------
extern "C" void kernel_launch(void* const* d_in, const int* in_sizes, int n_in,
                              void* d_out, int out_size, void* d_ws, size_t ws_size,
                              hipStream_t stream) {
    const float* pos = (const float*)d_in[0];
    const float* nrm = (const float*)d_in[1];
    const float* W1a = (const float*)d_in[3];
    const float* b1a = (const float*)d_in[4];
    const float* W1b = (const float*)d_in[5];
    const float* b1b = (const float*)d_in[6];
    const float* W2a = (const float*)d_in[7];
    const float* b2a = (const float*)d_in[8];
    const float* W2b = (const float*)d_in[9];
    const float* b2b = (const float*)d_in[10];
    const float* Wc  = (const float*)d_in[11];
    const float* bc  = (const float*)d_in[12];
    float* out = (float*)d_out;

    char* ws = (char*)d_ws;
    int*   nbr = (int*)(ws + OFF_NBR);
    float* ppf = (float*)(ws + OFF_PPF);
    float* G   = (float*)(ws + OFF_G);
    int*   pli = (int*)(ws + OFF_POOL);
    int*   ccnt = (int*)(ws + OFF_CNT);

    hipLaunchKernelGGL(knn_conv1,  dim3(2048), dim3(256), 0, stream,
                       pos, nrm, W1a, b1a, W1b, b1b, W2a, b2a, nbr, ppf, G, ccnt);
    hipLaunchKernelGGL(conv2_pool, dim3(2048), dim3(256), 0, stream,
                       ppf, nbr, G, W2a, W2b, b2b, Wc, bc, pli, ccnt, out);
}

// Round 9
// 195.701 us; speedup vs baseline: 2.1619x; 2.1619x over previous
//
#include <hip/hip_runtime.h>
#include <math.h>

// ---------------------------------------------------------------------------
// PPFNet pipeline on MI355X. B=16 clouds x 2048 pts, K=16 knn, all f32.
// 3 launches.
// Codegen lessons (r6/r7/r8): the conv2 edge-MLP body ONLY compiles well as
// r4's exact shape (1 edge/thread, h1[32]+acc[8], global h2 write, (256,4)
// bounds -> VGPR 52, no spill). Decorating it with LDS pool writes (r7) or
// an atomic fc tail (r8) makes the allocator squeeze to 28-32 VGPR and
// spill/churn (WRITE_SIZE 0.26->65858 KB, VALUBusy 83%->0.8%). Keep the fat
// kernel PURE; do pool+fc in a separate thin kernel.
//  K1 knn_conv1 : block = 256 = 16 points x 16 slices; whole cloud in LDS.
//     A: med3 top-4/slice of s=|c|^2-2p.c; B: shuffle bitonic -> tau;
//     C: rescan collect; D: exact-d2 fixup; E: nbr+ppf (poly atan2);
//     fused conv1 (edge-local) + gfromh (node-local) -> nbr, ppf, G.
//     Also zeroes the per-cloud fc counters for K3.
//  K2 conv2     : r4-exact. relu(G[j] + ppf@W2a[32:36]) -> 32x32 ->
//     16-lane shfl max -> h2 (global ws).
//  K3 pool_fc   : 128 blocks; block tree-reduce 256 nodes -> atomicMax per
//     cloud (h2>=0: int compare order-preserving; 0xAA poison negative =
//     identity); last of 8 blocks per cloud re-reads pooled via identity
//     atomicMax and computes Linear(32,40).
// ---------------------------------------------------------------------------

#define NPER 2048
#define NCLOUD 16

// ws layout (bytes)
#define OFF_NBR  (size_t)(0u)          // int   [N][16]    (2 MB)
#define OFF_PPF  (size_t)(2u << 20)    // float [N][16][4] (8 MB)
#define OFF_G    (size_t)(10u << 20)   // float [N][32]    (4 MB)
#define OFF_H2   (size_t)(14u << 20)   // float [N][32]    (4 MB)
#define OFF_POOL (size_t)(18u << 20)   // int   [16][32]   (2 KB)
#define OFF_CNT  ((size_t)(18u << 20) + 4096u)  // int [16]

__device__ __forceinline__ float med3(float a, float b, float c) {
    return __builtin_amdgcn_fmed3f(a, b, c);
}
__device__ __forceinline__ void cex(float& a, float& b) {
    const float lo = fminf(a, b), hi = fmaxf(a, b); a = lo; b = hi;
}
__device__ __forceinline__ void bmerge8(float (&v)[8]) {
#pragma unroll
    for (int i = 0; i < 4; ++i) cex(v[i], v[i + 4]);
#pragma unroll
    for (int b = 0; b < 8; b += 4)
#pragma unroll
        for (int i = 0; i < 2; ++i) cex(v[b + i], v[b + i + 2]);
#pragma unroll
    for (int b = 0; b < 8; b += 2) cex(v[b], v[b + 1]);
}
__device__ __forceinline__ void bmerge16(float (&v)[16]) {
#pragma unroll
    for (int i = 0; i < 8; ++i) cex(v[i], v[i + 8]);
#pragma unroll
    for (int b = 0; b < 16; b += 8)
#pragma unroll
        for (int i = 0; i < 4; ++i) cex(v[b + i], v[b + i + 4]);
#pragma unroll
    for (int b = 0; b < 16; b += 4)
#pragma unroll
        for (int i = 0; i < 2; ++i) cex(v[b + i], v[b + i + 2]);
#pragma unroll
    for (int b = 0; b < 16; b += 2) cex(v[b], v[b + 1]);
}

// atan2(y,x) with y >= 0, range [0,pi]. A&S 4.4.49 poly, err ~1e-6 rad.
__device__ __forceinline__ float fast_atan2p(float y, float x) {
    const float ax = fabsf(x);
    const float mn = fminf(ax, y), mx = fmaxf(ax, y);
    float a = mn * __builtin_amdgcn_rcpf(mx);
    a = (mx == 0.f) ? 0.f : a;
    const float t = a * a;
    float p = fmaf(t, 0.0028662257f, -0.0161657367f);
    p = fmaf(t, p, 0.0429096138f);
    p = fmaf(t, p, -0.0752896400f);
    p = fmaf(t, p, 0.1065626393f);
    p = fmaf(t, p, -0.1420889944f);
    p = fmaf(t, p, 0.1999355085f);
    p = fmaf(t, p, -0.3333314528f);
    float r = fmaf(a * t, p, a);                 // atan(a), a in [0,1]
    r = (y > ax) ? (1.5707963268f - r) : r;
    r = (x < 0.f) ? (3.1415926536f - r) : r;
    return r;
}

__device__ __forceinline__ float angf(float ax, float ay, float az,
                                      float bx, float by, float bz) {
    const float cx = ay * bz - az * by;
    const float cy = az * bx - ax * bz;
    const float cz = ax * by - ay * bx;
    const float cn = sqrtf(cx * cx + cy * cy + cz * cz);
    const float dt = ax * bx + ay * by + az * bz;
    return fast_atan2p(cn, dt);
}

// ---------------------------------------------------------------------------
// K1: knn + ppf + conv1 + gfromh. Block = 256 = 16 points x 16 slices.
// Grid = 2048. LDS ~33.5 KB -> 4 blocks/CU.
// ---------------------------------------------------------------------------
__global__ __launch_bounds__(256) void knn_conv1(const float* __restrict__ pos,
                                                 const float* __restrict__ nrm,
                                                 const float* __restrict__ W1a,
                                                 const float* __restrict__ b1a,
                                                 const float* __restrict__ W1b,
                                                 const float* __restrict__ b1b,
                                                 const float* __restrict__ W2a,
                                                 const float* __restrict__ b2a,
                                                 int* __restrict__ nbr,
                                                 float* __restrict__ ppf,
                                                 float* __restrict__ G,
                                                 int* __restrict__ ccnt) {
    const int tid = threadIdx.x;
    const int pl  = tid >> 4;               // point within block (0..15)
    const int sl  = tid & 15;               // slice / lane-in-node (0..15)
    const int gp  = blockIdx.x * 16 + pl;   // global point
    const int cloud = gp >> 11;
    const int lp  = gp & 2047;              // local point idx in cloud
    const int cbase = cloud * NPER;

    // zero the pool_fc last-block counters (kernel boundary = fence)
    if (blockIdx.x == 0 && tid < NCLOUD) ccnt[tid] = 0;

    __shared__ float4 tile[2048];           // x,y,z,|c|^2  (32 KB)
    __shared__ unsigned short hiL[16][40];  // hit local indices (1.25 KB)
    __shared__ int cnt[16];

    if (tid < 16) cnt[tid] = 0;

#pragma unroll
    for (int c = 0; c < 8; ++c) {
        const int idx = c * 256 + tid;
        const float x = pos[(cbase + idx) * 3 + 0];
        const float y = pos[(cbase + idx) * 3 + 1];
        const float z = pos[(cbase + idx) * 3 + 2];
        tile[idx] = make_float4(x, y, z, x * x + y * y + z * z);
    }
    __syncthreads();

    const float4 P  = tile[lp];
    const float pn2 = P.w;
    const float m2x = -2.f * P.x, m2y = -2.f * P.y, m2z = -2.f * P.z;

    // ---- Phase A: top-4 of s per slice (128 candidates), branchless ----
    float dl[4];
#pragma unroll
    for (int m = 0; m < 4; ++m) dl[m] = INFINITY;

#pragma unroll 4
    for (int jj = 0; jj < 128; ++jj) {
        const int cand = jj * 16 + sl;
        const float4 C = tile[cand];
        float s = fmaf(m2x, C.x, fmaf(m2y, C.y, fmaf(m2z, C.z, C.w)));
        s = (cand == lp) ? INFINITY : s;
        dl[3] = med3(dl[2], dl[3], s);
        dl[2] = med3(dl[1], dl[2], s);
        dl[1] = med3(dl[0], dl[1], s);
        dl[0] = fminf(dl[0], s);
    }

    // ---- Phase B: shuffle bitonic merge of 16 sorted-4 lists -> tau ----
    float tau_s;
    {
        float v8[8];
#pragma unroll
        for (int i = 0; i < 4; ++i) v8[i] = dl[i];
#pragma unroll
        for (int i = 0; i < 4; ++i) v8[7 - i] = __shfl_xor(dl[i], 1);
        bmerge8(v8);
        float v[16];
#pragma unroll
        for (int i = 0; i < 8; ++i) v[i] = v8[i];
#pragma unroll
        for (int i = 0; i < 8; ++i) v[15 - i] = __shfl_xor(v8[i], 2);
        bmerge16(v);
        {
            float p[16];
#pragma unroll
            for (int i = 0; i < 16; ++i) p[i] = __shfl_xor(v[i], 4);
            float w[16];
#pragma unroll
            for (int i = 0; i < 16; ++i) w[i] = fminf(v[i], p[15 - i]);
            bmerge16(w);
#pragma unroll
            for (int i = 0; i < 16; ++i) v[i] = w[i];
        }
        {
            float p[16];
#pragma unroll
            for (int i = 0; i < 16; ++i) p[i] = __shfl_xor(v[i], 8);
            float t = -INFINITY;
#pragma unroll
            for (int i = 0; i < 16; ++i) t = fmaxf(t, fminf(v[i], p[15 - i]));
            tau_s = t;
        }
    }
    const float tsw = tau_s + 6e-5f * (1.f + pn2 + fabsf(tau_s + pn2));

    // ---- Phase C: rescan on s, collect hit indices ----
#pragma unroll 4
    for (int jj = 0; jj < 128; ++jj) {
        const int cand = jj * 16 + sl;
        const float4 C = tile[cand];
        const float s = fmaf(m2x, C.x, fmaf(m2y, C.y, fmaf(m2z, C.z, C.w)));
        if (s <= tsw && cand != lp) {
            const int k = atomicAdd(&cnt[pl], 1);
            if (k < 40) hiL[pl][k] = (unsigned short)cand;
        }
    }
    __syncthreads();

    // ---- Phase D: exact top-16 (bit-identical d2, index tiebreak) ----
    if (tid < 16) {
        int n = cnt[tid];
        n = n > 40 ? 40 : n;
        if (n != 16) {
            const int myl = (blockIdx.x * 16 + tid) & 2047;
            const float4 Q = tile[myl];
            unsigned long long keys[16];
#pragma unroll
            for (int m = 0; m < 16; ++m) keys[m] = ~0ULL;
            for (int i = 0; i < n; ++i) {
                const int cand = hiL[tid][i];
                const float4 C = tile[cand];
                const float dx = __fsub_rn(Q.x, C.x);
                const float dy = __fsub_rn(Q.y, C.y);
                const float dz = __fsub_rn(Q.z, C.z);
                const float d2 = __fadd_rn(__fadd_rn(__fmul_rn(dx, dx),
                                                     __fmul_rn(dy, dy)),
                                           __fmul_rn(dz, dz));
                const unsigned long long key =
                    ((unsigned long long)__float_as_uint(d2) << 32) |
                    (unsigned int)cand;
                if (key < keys[15]) {
#pragma unroll
                    for (int m = 15; m >= 1; --m) {
                        const bool up   = key < keys[m - 1];
                        const bool here = key < keys[m];
                        keys[m] = up ? keys[m - 1] : (here ? key : keys[m]);
                    }
                    if (key < keys[0]) keys[0] = key;
                }
            }
#pragma unroll
            for (int m = 0; m < 16; ++m)
                hiL[tid][m] = (unsigned short)(keys[m] & 0xFFFFu);
        }
    }
    __syncthreads();

    // ---- Phase E: nbr + ppf (1 edge per thread, ppf kept in regs) ----
    const float nix = nrm[gp * 3 + 0], niy = nrm[gp * 3 + 1], niz = nrm[gp * 3 + 2];
    float4 x;
    {
        const int jl = hiL[pl][sl];
        const int j  = cbase + jl;
        nbr[gp * 16 + sl] = j;
        const float4 C = tile[jl];
        const float njx = nrm[j * 3 + 0], njy = nrm[j * 3 + 1], njz = nrm[j * 3 + 2];
        const float dx = C.x - P.x, dy = C.y - P.y, dz = C.z - P.z;
        x.x = sqrtf(dx * dx + dy * dy + dz * dz);
        x.y = angf(nix, niy, niz, dx, dy, dz);
        x.z = angf(njx, njy, njz, dx, dy, dz);
        x.w = angf(nix, niy, niz, njx, njy, njz);
        ((float4*)ppf)[(size_t)gp * 16 + sl] = x;
    }

    // ---- FUSED conv1: layer1 (4->32) on this edge ----
    float h1[32];
#pragma unroll
    for (int o = 0; o < 32; ++o) {
        h1[o] = fmaxf(fmaf(x.x, W1a[o],
                     fmaf(x.y, W1a[32 + o],
                     fmaf(x.z, W1a[64 + o],
                     fmaf(x.w, W1a[96 + o], b1a[o])))), 0.f);
    }

    // ---- layer2 (32->32) in 4x8 chunks + 16-lane max; all lanes keep h ----
    float hr[32];
#pragma unroll 1
    for (int ob = 0; ob < 4; ++ob) {
        float acc[8];
#pragma unroll
        for (int u = 0; u < 8; ++u) acc[u] = b1b[ob * 8 + u];
#pragma unroll
        for (int hh = 0; hh < 32; ++hh) {
            const float hv = h1[hh];
#pragma unroll
            for (int u = 0; u < 8; ++u)
                acc[u] = fmaf(hv, W1b[hh * 32 + ob * 8 + u], acc[u]);
        }
#pragma unroll
        for (int u = 0; u < 8; ++u) {
            float v = acc[u];
            v = fmaxf(v, __shfl_xor(v, 1));
            v = fmaxf(v, __shfl_xor(v, 2));
            v = fmaxf(v, __shfl_xor(v, 4));
            v = fmaxf(v, __shfl_xor(v, 8));
            hr[ob * 8 + u] = fmaxf(v, 0.f);
        }
    }

    // ---- FUSED gfromh: G[node] = hr @ W2a[0:32,:] + b2a (2 cols/lane) ----
    {
        const int c0 = sl * 2;
        float g0 = b2a[c0], g1 = b2a[c0 + 1];
#pragma unroll
        for (int k = 0; k < 32; ++k) {
            g0 = fmaf(hr[k], W2a[k * 32 + c0], g0);
            g1 = fmaf(hr[k], W2a[k * 32 + c0 + 1], g1);
        }
        ((float2*)(G + (size_t)gp * 32))[sl] = make_float2(g0, g1);
    }
}

// ---------------------------------------------------------------------------
// K2: conv2 (r4-exact proven codegen). 1 edge/thread, 16 threads/node.
// Grid 2048 x 256. Writes h2 to global ws.
// ---------------------------------------------------------------------------
__global__ __launch_bounds__(256, 4) void conv2_kernel(const float* __restrict__ ppf,
                                                       const int* __restrict__ nbr,
                                                       const float* __restrict__ G,
                                                       const float* __restrict__ W2a,
                                                       const float* __restrict__ W2b,
                                                       const float* __restrict__ b2b,
                                                       float* __restrict__ h2) {
    const int gid    = blockIdx.x * 256 + threadIdx.x;   // edge id
    const int node   = gid >> 4;
    const int lane16 = threadIdx.x & 15;

    const int j = nbr[gid];

    float h1[32];
    {
        const float4* gr = (const float4*)(G + (size_t)j * 32);
#pragma unroll
        for (int q = 0; q < 8; ++q) {
            const float4 v = gr[q];
            h1[q * 4 + 0] = v.x; h1[q * 4 + 1] = v.y;
            h1[q * 4 + 2] = v.z; h1[q * 4 + 3] = v.w;
        }
    }
    const float4 x = ((const float4*)ppf)[gid];
#pragma unroll
    for (int o = 0; o < 32; ++o) {
        h1[o] = fmaxf(fmaf(x.x, W2a[32 * 32 + o],
                     fmaf(x.y, W2a[33 * 32 + o],
                     fmaf(x.z, W2a[34 * 32 + o],
                     fmaf(x.w, W2a[35 * 32 + o], h1[o])))), 0.f);
    }

#pragma unroll 1
    for (int ob = 0; ob < 4; ++ob) {
        float acc[8];
#pragma unroll
        for (int u = 0; u < 8; ++u) acc[u] = b2b[ob * 8 + u];
#pragma unroll
        for (int hh = 0; hh < 32; ++hh) {
            const float hv = h1[hh];
#pragma unroll
            for (int u = 0; u < 8; ++u)
                acc[u] = fmaf(hv, W2b[hh * 32 + ob * 8 + u], acc[u]);
        }
#pragma unroll
        for (int u = 0; u < 8; ++u) {
            float v = acc[u];
            v = fmaxf(v, __shfl_xor(v, 1));
            v = fmaxf(v, __shfl_xor(v, 2));
            v = fmaxf(v, __shfl_xor(v, 4));
            v = fmaxf(v, __shfl_xor(v, 8));
            acc[u] = fmaxf(v, 0.f);
        }
        if (lane16 == 0) {
            float4* dst = (float4*)(h2 + (size_t)node * 32 + ob * 8);
            dst[0] = make_float4(acc[0], acc[1], acc[2], acc[3]);
            dst[1] = make_float4(acc[4], acc[5], acc[6], acc[7]);
        }
    }
}

// ---------------------------------------------------------------------------
// K3: pool + fc. Grid 128 x 256: 1 node/thread, block tree-reduce,
// int atomicMax per cloud; last of 8 blocks per cloud computes the
// Linear(32,40) (re-reads pooled via identity atomicMax).
// ---------------------------------------------------------------------------
__global__ __launch_bounds__(256) void pool_fc(const float* __restrict__ h2,
                                               const float* __restrict__ Wc,
                                               const float* __restrict__ bc,
                                               int* __restrict__ pooledi,
                                               int* __restrict__ ccnt,
                                               float* __restrict__ out) {
    const int tid   = threadIdx.x;
    const int node  = blockIdx.x * 256 + tid;
    const int cloud = node >> 11;

    float pm[32];
    const float4* row = (const float4*)(h2 + (size_t)node * 32);
#pragma unroll
    for (int q = 0; q < 8; ++q) {
        const float4 v = row[q];
        pm[q * 4 + 0] = v.x; pm[q * 4 + 1] = v.y;
        pm[q * 4 + 2] = v.z; pm[q * 4 + 3] = v.w;
    }

    __shared__ float red[256][33];
    __shared__ float red2[8][33];
    __shared__ float pv[32];
    __shared__ int lastFlag;
#pragma unroll
    for (int o = 0; o < 32; ++o) red[tid][o] = pm[o];
    __syncthreads();
    {
        const int oc = tid & 31, ch = tid >> 5;
        float m = -INFINITY;
#pragma unroll
        for (int r = 0; r < 32; ++r) m = fmaxf(m, red[ch * 32 + r][oc]);
        red2[ch][oc] = m;
    }
    __syncthreads();
    if (tid < 32) {
        float m = red2[0][tid];
#pragma unroll
        for (int c = 1; c < 8; ++c) m = fmaxf(m, red2[c][tid]);
        atomicMax(&pooledi[cloud * 32 + tid], __float_as_int(m));
    }

    __threadfence();
    if (tid == 0) lastFlag = (atomicAdd(&ccnt[cloud], 1) == 7);
    __syncthreads();
    if (lastFlag) {
        if (tid < 32) {
            // identity atomic read bypasses stale caches
            const int iv = atomicMax(&pooledi[cloud * 32 + tid],
                                     (int)0x80000000);
            pv[tid] = __int_as_float(iv);
        }
        __syncthreads();
        if (tid < 40) {
            float acc = bc[tid];
#pragma unroll
            for (int o = 0; o < 32; ++o)
                acc = fmaf(pv[o], Wc[o * 40 + tid], acc);
            out[cloud * 40 + tid] = acc;
        }
    }
}

// ---------------------------------------------------------------------------
extern "C" void kernel_launch(void* const* d_in, const int* in_sizes, int n_in,
                              void* d_out, int out_size, void* d_ws, size_t ws_size,
                              hipStream_t stream) {
    const float* pos = (const float*)d_in[0];
    const float* nrm = (const float*)d_in[1];
    const float* W1a = (const float*)d_in[3];
    const float* b1a = (const float*)d_in[4];
    const float* W1b = (const float*)d_in[5];
    const float* b1b = (const float*)d_in[6];
    const float* W2a = (const float*)d_in[7];
    const float* b2a = (const float*)d_in[8];
    const float* W2b = (const float*)d_in[9];
    const float* b2b = (const float*)d_in[10];
    const float* Wc  = (const float*)d_in[11];
    const float* bc  = (const float*)d_in[12];
    float* out = (float*)d_out;

    char* ws = (char*)d_ws;
    int*   nbr = (int*)(ws + OFF_NBR);
    float* ppf = (float*)(ws + OFF_PPF);
    float* G   = (float*)(ws + OFF_G);
    float* h2  = (float*)(ws + OFF_H2);
    int*   pli = (int*)(ws + OFF_POOL);
    int*   ccnt = (int*)(ws + OFF_CNT);

    hipLaunchKernelGGL(knn_conv1,    dim3(2048), dim3(256), 0, stream,
                       pos, nrm, W1a, b1a, W1b, b1b, W2a, b2a, nbr, ppf, G, ccnt);
    hipLaunchKernelGGL(conv2_kernel, dim3(2048), dim3(256), 0, stream,
                       ppf, nbr, G, W2a, W2b, b2b, h2);
    hipLaunchKernelGGL(pool_fc,      dim3(128),  dim3(256), 0, stream,
                       h2, Wc, bc, pli, ccnt, out);
}